// Round 1
// baseline (290.576 us; speedup 1.0000x reference)
//
#include <hip/hip_runtime.h>
#include <math.h>

typedef float f32x4 __attribute__((ext_vector_type(4)));

constexpr int kB = 8;
constexpr int kS = 4096;
constexpr int kF = 128;
constexpr int kT = 16;
constexpr int kNCHUNK = 64;            // S-chunks for the partial reduction
constexpr int kSCHUNK = kS / kNCHUNK;  // 64 s-steps per chunk

// ---------------- Kernel A1: partial sums of diff / diff^2 per (chunk,b,f) ----
__global__ __launch_bounds__(128) void std_partial_kernel(
    const float* __restrict__ x, double* __restrict__ psum, double* __restrict__ psq) {
    const int b = blockIdx.x / kNCHUNK;
    const int c = blockIdx.x % kNCHUNK;
    const int f = threadIdx.x;  // 0..127
    const long base = ((long)(b * kS + c * kSCHUNK)) * kF + f;
    // prev for first element of chunk: for global s==0 the reference diff is 0,
    // which falls out of prev = x[s=0] (cur - prev == 0).
    float prev = (c == 0) ? x[(long)b * kS * kF + f] : x[base - kF];
    double s1 = 0.0, s2 = 0.0;
    #pragma unroll 4
    for (int j = 0; j < kSCHUNK; ++j) {
        float cur = x[base + (long)j * kF];
        float d = cur - prev;   // exact f32 diff, matches reference bit-for-bit
        s1 += (double)d;
        s2 += (double)d * (double)d;
        prev = cur;
    }
    const int o = c * (kB * kF) + b * kF + f;
    psum[o] = s1;
    psq[o]  = s2;
}

// ---------------- Kernel A2: finish std, store denom = std_f32 + 1e-8f -------
__global__ __launch_bounds__(256) void std_finish_kernel(
    const double* __restrict__ psum, const double* __restrict__ psq,
    float* __restrict__ denom) {
    const int i = blockIdx.x * blockDim.x + threadIdx.x;  // [0, kB*kF)
    if (i >= kB * kF) return;
    double s1 = 0.0, s2 = 0.0;
    #pragma unroll 8
    for (int c = 0; c < kNCHUNK; ++c) {
        s1 += psum[c * (kB * kF) + i];
        s2 += psq[c * (kB * kF) + i];
    }
    const double mean = s1 / (double)kS;
    double var = s2 / (double)kS - mean * mean;
    if (var < 0.0) var = 0.0;
    const float stdf = (float)sqrt(var);   // np.std returns f32; double->f32 once
    denom[i] = stdf + 1e-8f;               // f32 add, matches (std + EPS) in f32
}

// ---------------- Fallback: direct std if ws too small (deterministic, slow) -
__global__ __launch_bounds__(128) void std_direct_kernel(
    const float* __restrict__ x, float* __restrict__ denom) {
    const int b = blockIdx.x;
    const int f = threadIdx.x;
    const long base = (long)b * kS * kF + f;
    float prev = x[base];
    double s1 = 0.0, s2 = 0.0;
    for (int s = 0; s < kS; ++s) {
        float cur = x[base + (long)s * kF];
        float d = cur - prev;
        s1 += (double)d;
        s2 += (double)d * (double)d;
        prev = cur;
    }
    const double mean = s1 / (double)kS;
    double var = s2 / (double)kS - mean * mean;
    if (var < 0.0) var = 0.0;
    denom[b * kF + f] = (float)sqrt(var) + 1e-8f;
}

// ---------------- Kernel B: compute spikes once, broadcast to 16 t-slices ----
// block = 256 threads: 8 s-rows x 32 float4-lanes (covers f=0..127)
// grid  = kB * (kS/8) = 4096 blocks
__global__ __launch_bounds__(256) void spike_write_kernel(
    const float* __restrict__ x, const float* __restrict__ denom,
    float* __restrict__ out) {
    const int tid = threadIdx.x;
    const int f4 = tid & 31;        // which float4 along F
    const int sl = tid >> 5;        // 0..7 local s row
    const int b  = blockIdx.x >> 9; // 512 s-chunks per b
    const int sc = blockIdx.x & 511;
    const int s  = sc * 8 + sl;

    const long inoff = ((long)(b * kS + s)) * kF + f4 * 4;
    const f32x4 cur  = *(const f32x4*)(x + inoff);
    const f32x4 prev = (s == 0) ? cur : *(const f32x4*)(x + inoff - kF);
    const f32x4 dn   = *(const f32x4*)(denom + b * kF + f4 * 4);

    f32x4 pos, neg;
    #pragma unroll
    for (int k = 0; k < 4; ++k) {
        const float d  = cur[k] - prev[k];
        const float nd = d / dn[k];              // f32 division, like reference
        pos[k] = (nd  >= 0.1f) ? 1.0f : 0.0f;
        neg[k] = (-nd >= 0.1f) ? 1.0f : 0.0f;
    }
    f32x4 zero;
    zero[0] = 0.0f; zero[1] = 0.0f; zero[2] = 0.0f; zero[3] = 0.0f;

    const long slice = (long)kS * kF;  // 524288 floats between t-slices
    const long outbase = (((long)b * kT) * kS + s) * kF + f4 * 4;
    #pragma unroll
    for (int t = 0; t < kT; ++t) {
        const int ph = t % 3;  // 0 -> pos, 1 -> neg, 2 -> silent
        const f32x4 v = (ph == 0) ? pos : ((ph == 1) ? neg : zero);
        __builtin_nontemporal_store(v, (f32x4*)(out + outbase + (long)t * slice));
    }
}

extern "C" void kernel_launch(void* const* d_in, const int* in_sizes, int n_in,
                              void* d_out, int out_size, void* d_ws, size_t ws_size,
                              hipStream_t stream) {
    const float* x = (const float*)d_in[0];
    float* out = (float*)d_out;

    // ws layout: [0,4KB) denom floats (1024); then 8B-aligned partial doubles
    float* denom = (float*)d_ws;
    double* psum = (double*)((char*)d_ws + 4096);
    double* psq  = psum + (size_t)kNCHUNK * kB * kF;
    const size_t needed = 4096 + 2ull * kNCHUNK * kB * kF * sizeof(double);

    if (ws_size >= needed) {
        std_partial_kernel<<<kB * kNCHUNK, 128, 0, stream>>>(x, psum, psq);
        std_finish_kernel<<<(kB * kF + 255) / 256, 256, 0, stream>>>(psum, psq, denom);
    } else {
        std_direct_kernel<<<kB, 128, 0, stream>>>(x, denom);
    }
    spike_write_kernel<<<kB * (kS / 8), 256, 0, stream>>>(x, denom, out);
}